// Round 9
// baseline (1086.827 us; speedup 1.0000x reference)
//
#include <hip/hip_runtime.h>
#include <hip/hip_bf16.h>
#include <stdint.h>

#define INPUT_DIM 1024
#define PRED_LEN 96
#define HIDDEN 512
#define BATCH 4096
#define W1_ROWS 1032  // INPUT_DIM + DAY_EMB

typedef __attribute__((ext_vector_type(8))) short bf16x8;
typedef __attribute__((ext_vector_type(4))) float floatx4;

__device__ __forceinline__ unsigned short f32_to_bf16_rne(float f) {
    union { float f; unsigned int u; } v; v.f = f;
    unsigned int u = v.u;
    unsigned int r = u + 0x7fffu + ((u >> 16) & 1u);
    return (unsigned short)(r >> 16);
}

__device__ __forceinline__ unsigned int pack_bf16x2(float lo, float hi) {
    return (unsigned int)f32_to_bf16_rne(lo) | ((unsigned int)f32_to_bf16_rne(hi) << 16);
}

__device__ __forceinline__ void async_copy16(const void* g, void* l) {
    __builtin_amdgcn_global_load_lds(
        (const __attribute__((address_space(1))) unsigned int*)g,
        (__attribute__((address_space(3))) unsigned int*)l, 16, 0, 0);
}

// --------------------------------------------------------------- fused prep
// Round-10 fused prep (harness-verified, unchanged). Transpose+convert W1x
// (blocks 0..3071), convert x (3072..5119), exact-f32 bias (5120..5215).
#define TP_BLOCKS  (PRED_LEN * 8 * 4)            // 3072: 64n x 256k tiles
#define CV_BLOCKS  ((BATCH * INPUT_DIM) / (256 * 8))  // 2048
__global__ void __launch_bounds__(256) prep_kernel(
        const float* __restrict__ x,
        const float* __restrict__ W1,
        const float* __restrict__ day_emb,
        const float* __restrict__ b1,
        unsigned short* __restrict__ xb,
        unsigned short* __restrict__ W1t,
        float* __restrict__ bias) {
    const int bid = blockIdx.x;
    const int t   = threadIdx.x;

    if (bid < TP_BLOCKS) {
        // ---- W1x transpose+convert: (p, k, n) f32 -> (p, n, k) bf16
        const int nt = bid & 7;          // n tile (64)
        const int kt = (bid >> 3) & 3;   // k tile (256)
        const int p  = bid >> 5;
        const int tn = t & 15;           // n-group: cols n0 + 4*tn .. +3
        const int tk = t >> 4;           // k-group: rows k0 + 16*tk .. +15
        const int n0 = nt * 64;
        const int k0 = kt * 256;

        const float* src = W1 + (size_t)p * W1_ROWS * HIDDEN
                              + (size_t)(k0 + 16 * tk) * HIDDEN + n0 + 4 * tn;
        float4 v[16];
        #pragma unroll
        for (int i = 0; i < 16; ++i)
            v[i] = *reinterpret_cast<const float4*>(src + (size_t)i * HIDDEN);

        size_t dst = ((size_t)p * HIDDEN + n0 + 4 * tn) * 1024 + k0 + 16 * tk;
        #pragma unroll
        for (int j = 0; j < 4; ++j) {
            float c[16];
            #pragma unroll
            for (int i = 0; i < 16; ++i)
                c[i] = (j == 0) ? v[i].x : (j == 1) ? v[i].y : (j == 2) ? v[i].z : v[i].w;
            uint4 o0, o1;
            o0.x = pack_bf16x2(c[0],  c[1]);
            o0.y = pack_bf16x2(c[2],  c[3]);
            o0.z = pack_bf16x2(c[4],  c[5]);
            o0.w = pack_bf16x2(c[6],  c[7]);
            o1.x = pack_bf16x2(c[8],  c[9]);
            o1.y = pack_bf16x2(c[10], c[11]);
            o1.z = pack_bf16x2(c[12], c[13]);
            o1.w = pack_bf16x2(c[14], c[15]);
            unsigned short* d = W1t + dst + (size_t)j * 1024;
            *reinterpret_cast<uint4*>(d)     = o0;
            *reinterpret_cast<uint4*>(d + 8) = o1;
        }
    } else if (bid < TP_BLOCKS + CV_BLOCKS) {
        // ---- convert x: 8 floats per thread, 16-B stores
        const int b = bid - TP_BLOCKS;
        const int i = (b * 256 + t) * 8;
        float4 a = *reinterpret_cast<const float4*>(x + i);
        float4 c = *reinterpret_cast<const float4*>(x + i + 4);
        uint4 o;
        o.x = pack_bf16x2(a.x, a.y);
        o.y = pack_bf16x2(a.z, a.w);
        o.z = pack_bf16x2(c.x, c.y);
        o.w = pack_bf16x2(c.z, c.w);
        *reinterpret_cast<uint4*>(xb + i) = o;
    } else {
        // ---- exact f32 bias: b1 + day_emb @ W1e   (2 h per thread)
        const int p = bid - (TP_BLOCKS + CV_BLOCKS);
        const float* W1e = W1 + ((size_t)p * W1_ROWS + INPUT_DIM) * HIDDEN;
        #pragma unroll
        for (int s = 0; s < 2; ++s) {
            const int h = t + s * 256;
            float acc = b1[p * HIDDEN + h];
            #pragma unroll
            for (int e = 0; e < 8; ++e)
                acc += day_emb[p * 8 + e] * W1e[(size_t)e * HIDDEN + h];
            bias[p * HIDDEN + h] = acc;
        }
    }
}

// ------------------------------------- fused GEMM + relu + W2 reduction + b2
// Round-14: A-OUT-OF-LDS. The model that fits all 9 rounds: LDS pipe is the
// wall. Round-0 = 96 KB LDS traffic/block-K-step (32 KB staged writes +
// 64 KB ds_reads); at 3 blocks/CU = 85 B/cyc = the m134 ds_read_b128
// ceiling; MfmaUtil 52% = MFMA demand / LDS time. Fix = remove traffic:
//  - A fragments global->VGPR, double-buffered at kk granularity (a0/a1).
//    Round-7 failed with these SAME addresses because loads sat 0 cycles
//    ahead of use; here each A-load has >=16 MFMAs (~310cy) + a read phase
//    of cover vs ~200-300cy L2 latency.
//  - B keeps the proven zero-conflict chunk-XOR staging, double-buffered
//    Bs[2] with round-8's counted vmcnt (never 0 in-loop). Issue order
//    A-kk1 -> B(k+1) -> compute keeps A always OLDER than B in the vmem
//    queue, so the compiler's automatic A-waits are vmcnt(8), never
//    draining B (oldest-first semantics, ledger audited per phase).
//  - LDS 38 KB -> 3 blocks/CU kept (round-8's fatal 2-block cost avoided).
// New LDS traffic 48 KB/block-step (~513cy) < MFMA 620cy -> MFMA-bound.
// Pre-commit: if >=360us, latency margin insufficient -> revert to round-0.
__global__ void __launch_bounds__(256, 3)
mlp_head_kernel(const unsigned short* __restrict__ xb,   // 4096x1024 bf16
                const unsigned short* __restrict__ W1t,  // 96x512x1024 bf16 (N-major)
                const float* __restrict__ bias,          // 96x512 f32
                const float* __restrict__ W2,            // 96x512 f32
                const float* __restrict__ b2,            // 96 f32
                float* __restrict__ out)                 // 4096x96 f32
{
    __shared__ unsigned short Bs[2][128 * 64];
    __shared__ float w2s[HIDDEN];
    __shared__ float biass[HIDDEN];
    __shared__ float red[2][128];

    const int mt   = blockIdx.x;  // 0..31 batch tile
    const int p    = blockIdx.y;  // 0..95
    const int t    = threadIdx.x;
    const int lane = t & 63;
    const int w    = t >> 6;
    const int wi   = w >> 1;      // row half (64)
    const int wj   = w & 1;       // col half (64)
    const int l15  = lane & 15;
    const int quad = lane >> 4;
    const int xl   = l15 & 7;     // row&7 for this lane's B fragment rows

    // B staging: thread stages LDS slot (row, t&7) with global chunk
    // (t&7)^(row&7); row = c*32 + (t>>3)
    const int t3    = t >> 3;                    // 0..31
    const int skc   = ((t & 7) ^ (t3 & 7)) * 8;  // swizzled k-offset (elems)
    const int ldsq8 = t * 8;                     // per-c LDS offset adds 2048

    for (int i = t; i < HIDDEN; i += 256) {
        w2s[i]   = W2[p * HIDDEN + i];
        biass[i] = bias[p * HIDDEN + i];
    }
    __syncthreads();  // drains vmcnt -> clean counting base

    const int m0 = mt * 128;
    // per-lane A base: row = m0 + wi*64 + l15, k = quad*8 (+i*16 rows, +kk*32)
    const unsigned short* agf = xb + (size_t)(m0 + wi * 64 + l15) * 1024 + quad * 8;
    const unsigned short* bg  = W1t + (size_t)p * HIDDEN * 1024 + (size_t)t3 * 1024 + skc;

    float partial[4][4];
    #pragma unroll
    for (int i = 0; i < 4; ++i)
        #pragma unroll
        for (int r = 0; r < 4; ++r) partial[i][r] = 0.f;

    floatx4 acc[4][4];
    #pragma unroll
    for (int i = 0; i < 4; ++i)
        #pragma unroll
        for (int j = 0; j < 4; ++j)
            acc[i][j] = (floatx4){0.f, 0.f, 0.f, 0.f};

    bf16x8 a0[4], a1[4];

    // ---- prologue: stage B(0) FIRST (so it is oldest), then A-kk0(0)
    #pragma unroll
    for (int c = 0; c < 4; ++c)
        async_copy16(bg + (size_t)c * 32768, &Bs[0][ldsq8 + c * 2048]);
    #pragma unroll
    for (int i = 0; i < 4; ++i)
        a0[i] = *reinterpret_cast<const bf16x8*>(agf + (size_t)i * 16384);
    // drain B(0) (oldest 4), leave a0 in flight
    asm volatile("s_waitcnt vmcnt(4)" ::: "memory");
    __builtin_amdgcn_s_barrier();

    #pragma unroll 1
    for (int vk = 0; vk < 64; ++vk) {
        const int cur = vk & 1;
        const int k0  = (vk & 15) << 6;

        // point 1: issue A-kk1(vk)  (k = k0 + 32)
        #pragma unroll
        for (int i = 0; i < 4; ++i)
            a1[i] = *reinterpret_cast<const bf16x8*>(agf + (size_t)i * 16384 + k0 + 32);

        // point 2: stage B(vk+1) into the other buffer
        if (vk < 63) {
            const int nvk    = vk + 1;
            const int k0n    = (nvk & 15) << 6;
            const size_t bnn = (size_t)(nvk >> 4) * 131072;
            #pragma unroll
            for (int c = 0; c < 4; ++c)
                async_copy16(bg + bnn + (size_t)c * 32768 + k0n,
                             &Bs[cur ^ 1][ldsq8 + c * 2048]);
        }

        // point 3: kk=0 -- B frags from Bs[cur], MFMA with a0 (compiler
        // waits a0: it is OLDEST in the vmem queue -> vmcnt(8), B stays)
        {
            const int slot = quad ^ xl;  // kk=0 swizzled chunk
            bf16x8 bfr[4];
            #pragma unroll
            for (int j = 0; j < 4; ++j) {
                int n = wj * 64 + j * 16 + l15;
                bfr[j] = *reinterpret_cast<const bf16x8*>(&Bs[cur][n * 64 + slot * 8]);
            }
            #pragma unroll
            for (int i = 0; i < 4; ++i)
                #pragma unroll
                for (int j = 0; j < 4; ++j)
                    acc[i][j] = __builtin_amdgcn_mfma_f32_16x16x32_bf16(
                        a0[i], bfr[j], acc[i][j], 0, 0, 0);
        }

        // point 4: issue A-kk0(vk+1) into a0 (its kk=0 MFMAs are done)
        if (vk < 63) {
            const int k0n = ((vk + 1) & 15) << 6;
            #pragma unroll
            for (int i = 0; i < 4; ++i)
                a0[i] = *reinterpret_cast<const bf16x8*>(agf + (size_t)i * 16384 + k0n);
        }

        // point 5: kk=1 -- MFMA with a1 (a1 older than B(vk+1), a0-next)
        {
            const int slot = (4 + quad) ^ xl;  // kk=1 swizzled chunk
            bf16x8 bfr[4];
            #pragma unroll
            for (int j = 0; j < 4; ++j) {
                int n = wj * 64 + j * 16 + l15;
                bfr[j] = *reinterpret_cast<const bf16x8*>(&Bs[cur][n * 64 + slot * 8]);
            }
            #pragma unroll
            for (int i = 0; i < 4; ++i)
                #pragma unroll
                for (int j = 0; j < 4; ++j)
                    acc[i][j] = __builtin_amdgcn_mfma_f32_16x16x32_bf16(
                        a1[i], bfr[j], acc[i][j], 0, 0, 0);
        }

        if ((vk & 15) == 15) {  // n-tile boundary: bias+relu+W2 fold, re-zero
            const int n0 = (vk >> 4) * 128;
            #pragma unroll
            for (int j = 0; j < 4; ++j) {
                int c = n0 + wj * 64 + j * 16 + l15;  // C layout: col = lane&15
                float w2v = w2s[c];
                float bv  = biass[c];
                #pragma unroll
                for (int i = 0; i < 4; ++i)
                    #pragma unroll
                    for (int r = 0; r < 4; ++r) {
                        float hv = acc[i][j][r] + bv;
                        hv = hv > 0.f ? hv : 0.f;
                        partial[i][r] += hv * w2v;
                        acc[i][j][r] = 0.f;
                    }
            }
        }

        // point 6: B(vk+1) landed (drain oldest 4 = B; a0-next stays), barrier
        if (vk < 63) {
            asm volatile("s_waitcnt vmcnt(4)" ::: "memory");
            asm volatile("" ::: "memory");
            __builtin_amdgcn_s_barrier();  // also: all reads of Bs[cur^1] done
            asm volatile("" ::: "memory");
        }
    }

    // reduce over columns: 16 lanes of each quad hold distinct cols of same rows
    #pragma unroll
    for (int i = 0; i < 4; ++i)
        #pragma unroll
        for (int r = 0; r < 4; ++r) {
            float v = partial[i][r];
            v += __shfl_xor(v, 1);
            v += __shfl_xor(v, 2);
            v += __shfl_xor(v, 4);
            v += __shfl_xor(v, 8);
            partial[i][r] = v;
        }

    if (l15 == 0) {
        #pragma unroll
        for (int i = 0; i < 4; ++i)
            #pragma unroll
            for (int r = 0; r < 4; ++r) {
                int row = wi * 64 + i * 16 + quad * 4 + r;  // C layout: row = quad*4+reg
                red[wj][row] = partial[i][r];
            }
    }
    __syncthreads();
    if (t < 128) {
        float v = red[0][t] + red[1][t] + b2[p];
        out[(size_t)(m0 + t) * PRED_LEN + p] = v;
    }
}

// ---------------------------------------------------------------------------
extern "C" void kernel_launch(void* const* d_in, const int* in_sizes, int n_in,
                              void* d_out, int out_size, void* d_ws, size_t ws_size,
                              hipStream_t stream) {
    const float* x       = (const float*)d_in[0];
    const float* day_emb = (const float*)d_in[1];
    const float* W1      = (const float*)d_in[2];
    const float* b1      = (const float*)d_in[3];
    const float* W2      = (const float*)d_in[4];
    const float* b2      = (const float*)d_in[5];
    float* out = (float*)d_out;

    const size_t xb_bytes  = (size_t)BATCH * INPUT_DIM * 2;             // 8,388,608
    const size_t w1t_bytes = (size_t)PRED_LEN * HIDDEN * INPUT_DIM * 2; // 100,663,296
    const size_t bias_bytes = (size_t)PRED_LEN * HIDDEN * 4;            // 196,608
    if (ws_size < xb_bytes + w1t_bytes + bias_bytes) return;

    unsigned short* xb  = (unsigned short*)d_ws;
    unsigned short* w1t = (unsigned short*)((char*)d_ws + xb_bytes);
    float* biasp        = (float*)((char*)d_ws + xb_bytes + w1t_bytes);

    prep_kernel<<<TP_BLOCKS + CV_BLOCKS + PRED_LEN, 256, 0, stream>>>(
        x, W1, day_emb, b1, xb, w1t, biasp);

    dim3 grid(BATCH / 128, PRED_LEN);
    mlp_head_kernel<<<grid, 256, 0, stream>>>(xb, w1t, biasp, W2, b2, out);
}

// Round 10
// 775.524 us; speedup vs baseline: 1.4014x; 1.4014x over previous
//
#include <hip/hip_runtime.h>
#include <hip/hip_bf16.h>
#include <stdint.h>

#define INPUT_DIM 1024
#define PRED_LEN 96
#define HIDDEN 512
#define BATCH 4096
#define W1_ROWS 1032  // INPUT_DIM + DAY_EMB

typedef __attribute__((ext_vector_type(8))) short bf16x8;
typedef __attribute__((ext_vector_type(4))) float floatx4;

__device__ __forceinline__ unsigned short f32_to_bf16_rne(float f) {
    union { float f; unsigned int u; } v; v.f = f;
    unsigned int u = v.u;
    unsigned int r = u + 0x7fffu + ((u >> 16) & 1u);
    return (unsigned short)(r >> 16);
}

__device__ __forceinline__ unsigned int pack_bf16x2(float lo, float hi) {
    return (unsigned int)f32_to_bf16_rne(lo) | ((unsigned int)f32_to_bf16_rne(hi) << 16);
}

__device__ __forceinline__ void async_copy16(const void* g, void* l) {
    __builtin_amdgcn_global_load_lds(
        (const __attribute__((address_space(1))) unsigned int*)g,
        (__attribute__((address_space(3))) unsigned int*)l, 16, 0, 0);
}

// --------------------------------------------------------------- fused prep
// Round-10 fused prep (harness-verified, unchanged). Transpose+convert W1x
// (blocks 0..3071), convert x (3072..5119), exact-f32 bias (5120..5215).
#define TP_BLOCKS  (PRED_LEN * 8 * 4)            // 3072: 64n x 256k tiles
#define CV_BLOCKS  ((BATCH * INPUT_DIM) / (256 * 8))  // 2048
__global__ void __launch_bounds__(256) prep_kernel(
        const float* __restrict__ x,
        const float* __restrict__ W1,
        const float* __restrict__ day_emb,
        const float* __restrict__ b1,
        unsigned short* __restrict__ xb,
        unsigned short* __restrict__ W1t,
        float* __restrict__ bias) {
    const int bid = blockIdx.x;
    const int t   = threadIdx.x;

    if (bid < TP_BLOCKS) {
        // ---- W1x transpose+convert: (p, k, n) f32 -> (p, n, k) bf16
        const int nt = bid & 7;          // n tile (64)
        const int kt = (bid >> 3) & 3;   // k tile (256)
        const int p  = bid >> 5;
        const int tn = t & 15;           // n-group: cols n0 + 4*tn .. +3
        const int tk = t >> 4;           // k-group: rows k0 + 16*tk .. +15
        const int n0 = nt * 64;
        const int k0 = kt * 256;

        const float* src = W1 + (size_t)p * W1_ROWS * HIDDEN
                              + (size_t)(k0 + 16 * tk) * HIDDEN + n0 + 4 * tn;
        float4 v[16];
        #pragma unroll
        for (int i = 0; i < 16; ++i)
            v[i] = *reinterpret_cast<const float4*>(src + (size_t)i * HIDDEN);

        size_t dst = ((size_t)p * HIDDEN + n0 + 4 * tn) * 1024 + k0 + 16 * tk;
        #pragma unroll
        for (int j = 0; j < 4; ++j) {
            float c[16];
            #pragma unroll
            for (int i = 0; i < 16; ++i)
                c[i] = (j == 0) ? v[i].x : (j == 1) ? v[i].y : (j == 2) ? v[i].z : v[i].w;
            uint4 o0, o1;
            o0.x = pack_bf16x2(c[0],  c[1]);
            o0.y = pack_bf16x2(c[2],  c[3]);
            o0.z = pack_bf16x2(c[4],  c[5]);
            o0.w = pack_bf16x2(c[6],  c[7]);
            o1.x = pack_bf16x2(c[8],  c[9]);
            o1.y = pack_bf16x2(c[10], c[11]);
            o1.z = pack_bf16x2(c[12], c[13]);
            o1.w = pack_bf16x2(c[14], c[15]);
            unsigned short* d = W1t + dst + (size_t)j * 1024;
            *reinterpret_cast<uint4*>(d)     = o0;
            *reinterpret_cast<uint4*>(d + 8) = o1;
        }
    } else if (bid < TP_BLOCKS + CV_BLOCKS) {
        // ---- convert x: 8 floats per thread, 16-B stores
        const int b = bid - TP_BLOCKS;
        const int i = (b * 256 + t) * 8;
        float4 a = *reinterpret_cast<const float4*>(x + i);
        float4 c = *reinterpret_cast<const float4*>(x + i + 4);
        uint4 o;
        o.x = pack_bf16x2(a.x, a.y);
        o.y = pack_bf16x2(a.z, a.w);
        o.z = pack_bf16x2(c.x, c.y);
        o.w = pack_bf16x2(c.z, c.w);
        *reinterpret_cast<uint4*>(xb + i) = o;
    } else {
        // ---- exact f32 bias: b1 + day_emb @ W1e   (2 h per thread)
        const int p = bid - (TP_BLOCKS + CV_BLOCKS);
        const float* W1e = W1 + ((size_t)p * W1_ROWS + INPUT_DIM) * HIDDEN;
        #pragma unroll
        for (int s = 0; s < 2; ++s) {
            const int h = t + s * 256;
            float acc = b1[p * HIDDEN + h];
            #pragma unroll
            for (int e = 0; e < 8; ++e)
                acc += day_emb[p * 8 + e] * W1e[(size_t)e * HIDDEN + h];
            bias[p * HIDDEN + h] = acc;
        }
    }
}

// ------------------------------------- fused GEMM + relu + W2 reduction + b2
// Round-15: WIDE-N TILE. The model fitting all 10 rounds: LDS pipe is the
// wall (round-0 per-CU traffic 12 blocks x 6 MB = 72 MB / 85 B/cyc = 847k
// cyc ~ measured 882k wall). Scheduling can't beat it (r1,r2,r3,r8);
// A-from-global can't either (r7,r9: xb 8MB > 4MB L2/XCD -> L3-latency
// bound). Only traffic/MFMA can: block stages A 128x64 + B 256x64/K-step;
// 2x2 waves each compute 64x128 (acc[4][8], 128 AGPR; unified-file fits at
// 3 waves/SIMD). Reads/step = 2*16+2*32 = 96 KB for 2x MFMA: traffic/MFMA
// 0.75 -> 0.5625 KB. A-writes halve; steps 64->32 so barriers + latency
// exposures halve. LDS 52 KB (red aliased onto dead As) -> 3 blocks/CU
// KEPT (r8's fatal cost avoided). Everything else is round-0 verbatim:
// zero-conflict chunk-XOR swizzle, full-line staging, 2-barrier K-step,
// epilogue algebra. Per-CU model: 12 x 4.5 MB = 54 MB / 85 = 635k cyc
// -> ~270-300 us predicted.
__global__ void __launch_bounds__(256, 3)
mlp_head_kernel(const unsigned short* __restrict__ xb,   // 4096x1024 bf16
                const unsigned short* __restrict__ W1t,  // 96x512x1024 bf16 (N-major)
                const float* __restrict__ bias,          // 96x512 f32
                const float* __restrict__ W2,            // 96x512 f32
                const float* __restrict__ b2,            // 96 f32
                float* __restrict__ out)                 // 4096x96 f32
{
    __shared__ unsigned short As[128 * 64];   // 16 KB  (red[] aliases this at the end)
    __shared__ unsigned short Bs[256 * 64];   // 32 KB
    __shared__ float w2s[HIDDEN];             // 2 KB
    __shared__ float biass[HIDDEN];           // 2 KB

    const int mt   = blockIdx.x;  // 0..31 batch tile
    const int p    = blockIdx.y;  // 0..95
    const int t    = threadIdx.x;
    const int lane = t & 63;
    const int w    = t >> 6;
    const int wi   = w >> 1;      // row half (64)
    const int wj   = w & 1;       // col half (128)
    const int l15  = lane & 15;
    const int quad = lane >> 4;
    const int xl   = l15 & 7;     // row&7 for all this lane's fragment rows

    // staging constants: thread stages LDS slot (row, t&7) with global chunk
    // (t&7)^(row&7); row = c*32 + (t>>3)   (c: 0..3 for A, 0..7 for B)
    const int t3    = t >> 3;                    // 0..31
    const int skc   = ((t & 7) ^ (t3 & 7)) * 8;  // swizzled k-offset (elems)
    const int ldsq8 = t * 8;                     // per-c LDS offset adds 2048

    for (int i = t; i < HIDDEN; i += 256) {
        w2s[i]   = W2[p * HIDDEN + i];
        biass[i] = bias[p * HIDDEN + i];
    }

    const int m0 = mt * 128;
    const unsigned short* ag = xb  + (size_t)m0 * 1024 + (size_t)t3 * 1024 + skc;
    const unsigned short* bg = W1t + (size_t)p * HIDDEN * 1024 + (size_t)t3 * 1024 + skc;

    float partial[4][4];
    #pragma unroll
    for (int i = 0; i < 4; ++i)
        #pragma unroll
        for (int r = 0; r < 4; ++r) partial[i][r] = 0.f;

    floatx4 acc[4][8];
    #pragma unroll
    for (int i = 0; i < 4; ++i)
        #pragma unroll
        for (int j = 0; j < 8; ++j)
            acc[i][j] = (floatx4){0.f, 0.f, 0.f, 0.f};

    // 32 virtual K-steps: vk>>4 = nt (0..1, 256-col tiles), vk&15 = K-chunk
    #pragma unroll 1
    for (int vk = 0; vk < 32; ++vk) {
        const int k0 = (vk & 15) << 6;
        const size_t bnn = (size_t)(vk >> 4) * 262144;  // nt * 256 rows * 1024

        __syncthreads();  // prior K-step's ds_reads complete
        #pragma unroll
        for (int c = 0; c < 4; ++c)
            async_copy16(ag + (size_t)c * 32768 + k0, As + ldsq8 + c * 2048);
        #pragma unroll
        for (int c = 0; c < 8; ++c)
            async_copy16(bg + bnn + (size_t)c * 32768 + k0, Bs + ldsq8 + c * 2048);
        __syncthreads();  // staging visible (vmcnt drained by barrier)

        #pragma unroll
        for (int kk = 0; kk < 2; ++kk) {
            const int slot = (kk * 4 + quad) ^ xl;  // swizzled chunk position
            bf16x8 af[4], bfr[8];
            #pragma unroll
            for (int i = 0; i < 4; ++i) {
                int r = wi * 64 + i * 16 + l15;
                af[i] = *reinterpret_cast<const bf16x8*>(As + r * 64 + slot * 8);
            }
            #pragma unroll
            for (int j = 0; j < 8; ++j) {
                int n = wj * 128 + j * 16 + l15;   // n&7 == l15&7, swizzle holds
                bfr[j] = *reinterpret_cast<const bf16x8*>(Bs + n * 64 + slot * 8);
            }
            #pragma unroll
            for (int i = 0; i < 4; ++i)
                #pragma unroll
                for (int j = 0; j < 8; ++j)
                    acc[i][j] = __builtin_amdgcn_mfma_f32_16x16x32_bf16(
                        af[i], bfr[j], acc[i][j], 0, 0, 0);
        }

        if ((vk & 15) == 15) {  // n-tile boundary: bias+relu+W2 fold, re-zero
            const int n0 = (vk >> 4) * 256;
            #pragma unroll
            for (int j = 0; j < 8; ++j) {
                int c = n0 + wj * 128 + j * 16 + l15;  // C layout: col = lane&15
                float w2v = w2s[c];
                float bv  = biass[c];
                #pragma unroll
                for (int i = 0; i < 4; ++i)
                    #pragma unroll
                    for (int r = 0; r < 4; ++r) {
                        float hv = acc[i][j][r] + bv;
                        hv = hv > 0.f ? hv : 0.f;
                        partial[i][r] += hv * w2v;
                        acc[i][j][r] = 0.f;
                    }
            }
        }
    }

    // reduce over columns: 16 lanes of each quad hold distinct cols of same rows
    #pragma unroll
    for (int i = 0; i < 4; ++i)
        #pragma unroll
        for (int r = 0; r < 4; ++r) {
            float v = partial[i][r];
            v += __shfl_xor(v, 1);
            v += __shfl_xor(v, 2);
            v += __shfl_xor(v, 4);
            v += __shfl_xor(v, 8);
            partial[i][r] = v;
        }

    __syncthreads();  // all As reads done -> safe to alias red onto As
    float* red = reinterpret_cast<float*>(As);  // red[2][128], 1 KB of dead As

    if (l15 == 0) {
        #pragma unroll
        for (int i = 0; i < 4; ++i)
            #pragma unroll
            for (int r = 0; r < 4; ++r) {
                int row = wi * 64 + i * 16 + quad * 4 + r;  // C layout: row = quad*4+reg
                red[wj * 128 + row] = partial[i][r];
            }
    }
    __syncthreads();
    if (t < 128) {
        float v = red[t] + red[128 + t] + b2[p];
        out[(size_t)(m0 + t) * PRED_LEN + p] = v;
    }
}

// ---------------------------------------------------------------------------
extern "C" void kernel_launch(void* const* d_in, const int* in_sizes, int n_in,
                              void* d_out, int out_size, void* d_ws, size_t ws_size,
                              hipStream_t stream) {
    const float* x       = (const float*)d_in[0];
    const float* day_emb = (const float*)d_in[1];
    const float* W1      = (const float*)d_in[2];
    const float* b1      = (const float*)d_in[3];
    const float* W2      = (const float*)d_in[4];
    const float* b2      = (const float*)d_in[5];
    float* out = (float*)d_out;

    const size_t xb_bytes  = (size_t)BATCH * INPUT_DIM * 2;             // 8,388,608
    const size_t w1t_bytes = (size_t)PRED_LEN * HIDDEN * INPUT_DIM * 2; // 100,663,296
    const size_t bias_bytes = (size_t)PRED_LEN * HIDDEN * 4;            // 196,608
    if (ws_size < xb_bytes + w1t_bytes + bias_bytes) return;

    unsigned short* xb  = (unsigned short*)d_ws;
    unsigned short* w1t = (unsigned short*)((char*)d_ws + xb_bytes);
    float* biasp        = (float*)((char*)d_ws + xb_bytes + w1t_bytes);

    prep_kernel<<<TP_BLOCKS + CV_BLOCKS + PRED_LEN, 256, 0, stream>>>(
        x, W1, day_emb, b1, xb, w1t, biasp);

    dim3 grid(BATCH / 128, PRED_LEN);
    mlp_head_kernel<<<grid, 256, 0, stream>>>(xb, w1t, biasp, W2, b2, out);
}

// Round 11
// 641.815 us; speedup vs baseline: 1.6934x; 1.2083x over previous
//
#include <hip/hip_runtime.h>
#include <hip/hip_bf16.h>
#include <stdint.h>

#define INPUT_DIM 1024
#define PRED_LEN 96
#define HIDDEN 512
#define BATCH 4096
#define W1_ROWS 1032  // INPUT_DIM + DAY_EMB

typedef __attribute__((ext_vector_type(8))) short bf16x8;
typedef __attribute__((ext_vector_type(4))) float floatx4;

__device__ __forceinline__ unsigned short f32_to_bf16_rne(float f) {
    union { float f; unsigned int u; } v; v.f = f;
    unsigned int u = v.u;
    unsigned int r = u + 0x7fffu + ((u >> 16) & 1u);
    return (unsigned short)(r >> 16);
}

__device__ __forceinline__ unsigned int pack_bf16x2(float lo, float hi) {
    return (unsigned int)f32_to_bf16_rne(lo) | ((unsigned int)f32_to_bf16_rne(hi) << 16);
}

__device__ __forceinline__ void async_copy16(const void* g, void* l) {
    __builtin_amdgcn_global_load_lds(
        (const __attribute__((address_space(1))) unsigned int*)g,
        (__attribute__((address_space(3))) unsigned int*)l, 16, 0, 0);
}

// --------------------------------------------------------------- fused prep
// Round-10 fused prep (harness-verified, unchanged). Transpose+convert W1x
// (blocks 0..3071), convert x (3072..5119), exact-f32 bias (5120..5215).
#define TP_BLOCKS  (PRED_LEN * 8 * 4)            // 3072: 64n x 256k tiles
#define CV_BLOCKS  ((BATCH * INPUT_DIM) / (256 * 8))  // 2048
__global__ void __launch_bounds__(256) prep_kernel(
        const float* __restrict__ x,
        const float* __restrict__ W1,
        const float* __restrict__ day_emb,
        const float* __restrict__ b1,
        unsigned short* __restrict__ xb,
        unsigned short* __restrict__ W1t,
        float* __restrict__ bias) {
    const int bid = blockIdx.x;
    const int t   = threadIdx.x;

    if (bid < TP_BLOCKS) {
        // ---- W1x transpose+convert: (p, k, n) f32 -> (p, n, k) bf16
        const int nt = bid & 7;          // n tile (64)
        const int kt = (bid >> 3) & 3;   // k tile (256)
        const int p  = bid >> 5;
        const int tn = t & 15;           // n-group: cols n0 + 4*tn .. +3
        const int tk = t >> 4;           // k-group: rows k0 + 16*tk .. +15
        const int n0 = nt * 64;
        const int k0 = kt * 256;

        const float* src = W1 + (size_t)p * W1_ROWS * HIDDEN
                              + (size_t)(k0 + 16 * tk) * HIDDEN + n0 + 4 * tn;
        float4 v[16];
        #pragma unroll
        for (int i = 0; i < 16; ++i)
            v[i] = *reinterpret_cast<const float4*>(src + (size_t)i * HIDDEN);

        size_t dst = ((size_t)p * HIDDEN + n0 + 4 * tn) * 1024 + k0 + 16 * tk;
        #pragma unroll
        for (int j = 0; j < 4; ++j) {
            float c[16];
            #pragma unroll
            for (int i = 0; i < 16; ++i)
                c[i] = (j == 0) ? v[i].x : (j == 1) ? v[i].y : (j == 2) ? v[i].z : v[i].w;
            uint4 o0, o1;
            o0.x = pack_bf16x2(c[0],  c[1]);
            o0.y = pack_bf16x2(c[2],  c[3]);
            o0.z = pack_bf16x2(c[4],  c[5]);
            o0.w = pack_bf16x2(c[6],  c[7]);
            o1.x = pack_bf16x2(c[8],  c[9]);
            o1.y = pack_bf16x2(c[10], c[11]);
            o1.z = pack_bf16x2(c[12], c[13]);
            o1.w = pack_bf16x2(c[14], c[15]);
            unsigned short* d = W1t + dst + (size_t)j * 1024;
            *reinterpret_cast<uint4*>(d)     = o0;
            *reinterpret_cast<uint4*>(d + 8) = o1;
        }
    } else if (bid < TP_BLOCKS + CV_BLOCKS) {
        // ---- convert x: 8 floats per thread, 16-B stores
        const int b = bid - TP_BLOCKS;
        const int i = (b * 256 + t) * 8;
        float4 a = *reinterpret_cast<const float4*>(x + i);
        float4 c = *reinterpret_cast<const float4*>(x + i + 4);
        uint4 o;
        o.x = pack_bf16x2(a.x, a.y);
        o.y = pack_bf16x2(a.z, a.w);
        o.z = pack_bf16x2(c.x, c.y);
        o.w = pack_bf16x2(c.z, c.w);
        *reinterpret_cast<uint4*>(xb + i) = o;
    } else {
        // ---- exact f32 bias: b1 + day_emb @ W1e   (2 h per thread)
        const int p = bid - (TP_BLOCKS + CV_BLOCKS);
        const float* W1e = W1 + ((size_t)p * W1_ROWS + INPUT_DIM) * HIDDEN;
        #pragma unroll
        for (int s = 0; s < 2; ++s) {
            const int h = t + s * 256;
            float acc = b1[p * HIDDEN + h];
            #pragma unroll
            for (int e = 0; e < 8; ++e)
                acc += day_emb[p * 8 + e] * W1e[(size_t)e * HIDDEN + h];
            bias[p * HIDDEN + h] = acc;
        }
    }
}

// ------------------------------------- fused GEMM + relu + W2 reduction + b2
// Round-16: wide-N tile, SPILL FIXED. Round-10's WRITE_SIZE=467 MB was the
// acc[4][8] (128 regs) spilling wholesale under (256,3)'s ~170-reg cap
// (152 KB written/block = 128regs x 256thr x 4B). The tile needs ~218 regs
// -> HW fits floor(512/218) = 2 waves/SIMD, so the honest bound is
// __launch_bounds__(256, 2) -- the ONLY change vs round-10.
// Traffic model (the one fitting all rounds): LDS pipe is the wall.
// Wide-N: reads 96 KB + writes 48 KB per block-step for 256 MFMA
// (0.5625 KB/MFMA vs round-0's 0.75); steps 64->32 halves barriers.
// At 2 blocks/CU: LDS ~3008 cyc/round >= MFMA 2480 -> 192 rounds/CU
// -> ~270 us + latency exposure -> predict 290-380.
// Pre-commit: >=360 us with spills gone -> revert to round-0 mlp, declare
// floor. (r7/r9: A-from-global dead, xb > 4MB L2/XCD. r6: XCD swizzle dead,
// placement not bid&7. r1/r2/r3/r8: scheduling dead, LDS-BW-bound.)
__global__ void __launch_bounds__(256, 2)
mlp_head_kernel(const unsigned short* __restrict__ xb,   // 4096x1024 bf16
                const unsigned short* __restrict__ W1t,  // 96x512x1024 bf16 (N-major)
                const float* __restrict__ bias,          // 96x512 f32
                const float* __restrict__ W2,            // 96x512 f32
                const float* __restrict__ b2,            // 96 f32
                float* __restrict__ out)                 // 4096x96 f32
{
    __shared__ unsigned short As[128 * 64];   // 16 KB  (red[] aliases this at the end)
    __shared__ unsigned short Bs[256 * 64];   // 32 KB
    __shared__ float w2s[HIDDEN];             // 2 KB
    __shared__ float biass[HIDDEN];           // 2 KB

    const int mt   = blockIdx.x;  // 0..31 batch tile
    const int p    = blockIdx.y;  // 0..95
    const int t    = threadIdx.x;
    const int lane = t & 63;
    const int w    = t >> 6;
    const int wi   = w >> 1;      // row half (64)
    const int wj   = w & 1;       // col half (128)
    const int l15  = lane & 15;
    const int quad = lane >> 4;
    const int xl   = l15 & 7;     // row&7 for all this lane's fragment rows

    // staging constants: thread stages LDS slot (row, t&7) with global chunk
    // (t&7)^(row&7); row = c*32 + (t>>3)   (c: 0..3 for A, 0..7 for B)
    const int t3    = t >> 3;                    // 0..31
    const int skc   = ((t & 7) ^ (t3 & 7)) * 8;  // swizzled k-offset (elems)
    const int ldsq8 = t * 8;                     // per-c LDS offset adds 2048

    for (int i = t; i < HIDDEN; i += 256) {
        w2s[i]   = W2[p * HIDDEN + i];
        biass[i] = bias[p * HIDDEN + i];
    }

    const int m0 = mt * 128;
    const unsigned short* ag = xb  + (size_t)m0 * 1024 + (size_t)t3 * 1024 + skc;
    const unsigned short* bg = W1t + (size_t)p * HIDDEN * 1024 + (size_t)t3 * 1024 + skc;

    float partial[4][4];
    #pragma unroll
    for (int i = 0; i < 4; ++i)
        #pragma unroll
        for (int r = 0; r < 4; ++r) partial[i][r] = 0.f;

    floatx4 acc[4][8];
    #pragma unroll
    for (int i = 0; i < 4; ++i)
        #pragma unroll
        for (int j = 0; j < 8; ++j)
            acc[i][j] = (floatx4){0.f, 0.f, 0.f, 0.f};

    // 32 virtual K-steps: vk>>4 = nt (0..1, 256-col tiles), vk&15 = K-chunk
    #pragma unroll 1
    for (int vk = 0; vk < 32; ++vk) {
        const int k0 = (vk & 15) << 6;
        const size_t bnn = (size_t)(vk >> 4) * 262144;  // nt * 256 rows * 1024

        __syncthreads();  // prior K-step's ds_reads complete
        #pragma unroll
        for (int c = 0; c < 4; ++c)
            async_copy16(ag + (size_t)c * 32768 + k0, As + ldsq8 + c * 2048);
        #pragma unroll
        for (int c = 0; c < 8; ++c)
            async_copy16(bg + bnn + (size_t)c * 32768 + k0, Bs + ldsq8 + c * 2048);
        __syncthreads();  // staging visible (vmcnt drained by barrier)

        #pragma unroll
        for (int kk = 0; kk < 2; ++kk) {
            const int slot = (kk * 4 + quad) ^ xl;  // swizzled chunk position
            bf16x8 af[4], bfr[8];
            #pragma unroll
            for (int i = 0; i < 4; ++i) {
                int r = wi * 64 + i * 16 + l15;
                af[i] = *reinterpret_cast<const bf16x8*>(As + r * 64 + slot * 8);
            }
            #pragma unroll
            for (int j = 0; j < 8; ++j) {
                int n = wj * 128 + j * 16 + l15;   // n&7 == l15&7, swizzle holds
                bfr[j] = *reinterpret_cast<const bf16x8*>(Bs + n * 64 + slot * 8);
            }
            #pragma unroll
            for (int i = 0; i < 4; ++i)
                #pragma unroll
                for (int j = 0; j < 8; ++j)
                    acc[i][j] = __builtin_amdgcn_mfma_f32_16x16x32_bf16(
                        af[i], bfr[j], acc[i][j], 0, 0, 0);
        }

        if ((vk & 15) == 15) {  // n-tile boundary: bias+relu+W2 fold, re-zero
            const int n0 = (vk >> 4) * 256;
            #pragma unroll
            for (int j = 0; j < 8; ++j) {
                int c = n0 + wj * 128 + j * 16 + l15;  // C layout: col = lane&15
                float w2v = w2s[c];
                float bv  = biass[c];
                #pragma unroll
                for (int i = 0; i < 4; ++i)
                    #pragma unroll
                    for (int r = 0; r < 4; ++r) {
                        float hv = acc[i][j][r] + bv;
                        hv = hv > 0.f ? hv : 0.f;
                        partial[i][r] += hv * w2v;
                        acc[i][j][r] = 0.f;
                    }
            }
        }
    }

    // reduce over columns: 16 lanes of each quad hold distinct cols of same rows
    #pragma unroll
    for (int i = 0; i < 4; ++i)
        #pragma unroll
        for (int r = 0; r < 4; ++r) {
            float v = partial[i][r];
            v += __shfl_xor(v, 1);
            v += __shfl_xor(v, 2);
            v += __shfl_xor(v, 4);
            v += __shfl_xor(v, 8);
            partial[i][r] = v;
        }

    __syncthreads();  // all As reads done -> safe to alias red onto As
    float* red = reinterpret_cast<float*>(As);  // red[2][128], 1 KB of dead As

    if (l15 == 0) {
        #pragma unroll
        for (int i = 0; i < 4; ++i)
            #pragma unroll
            for (int r = 0; r < 4; ++r) {
                int row = wi * 64 + i * 16 + quad * 4 + r;  // C layout: row = quad*4+reg
                red[wj * 128 + row] = partial[i][r];
            }
    }
    __syncthreads();
    if (t < 128) {
        float v = red[t] + red[128 + t] + b2[p];
        out[(size_t)(m0 + t) * PRED_LEN + p] = v;
    }
}

// ---------------------------------------------------------------------------
extern "C" void kernel_launch(void* const* d_in, const int* in_sizes, int n_in,
                              void* d_out, int out_size, void* d_ws, size_t ws_size,
                              hipStream_t stream) {
    const float* x       = (const float*)d_in[0];
    const float* day_emb = (const float*)d_in[1];
    const float* W1      = (const float*)d_in[2];
    const float* b1      = (const float*)d_in[3];
    const float* W2      = (const float*)d_in[4];
    const float* b2      = (const float*)d_in[5];
    float* out = (float*)d_out;

    const size_t xb_bytes  = (size_t)BATCH * INPUT_DIM * 2;             // 8,388,608
    const size_t w1t_bytes = (size_t)PRED_LEN * HIDDEN * INPUT_DIM * 2; // 100,663,296
    const size_t bias_bytes = (size_t)PRED_LEN * HIDDEN * 4;            // 196,608
    if (ws_size < xb_bytes + w1t_bytes + bias_bytes) return;

    unsigned short* xb  = (unsigned short*)d_ws;
    unsigned short* w1t = (unsigned short*)((char*)d_ws + xb_bytes);
    float* biasp        = (float*)((char*)d_ws + xb_bytes + w1t_bytes);

    prep_kernel<<<TP_BLOCKS + CV_BLOCKS + PRED_LEN, 256, 0, stream>>>(
        x, W1, day_emb, b1, xb, w1t, biasp);

    dim3 grid(BATCH / 128, PRED_LEN);
    mlp_head_kernel<<<grid, 256, 0, stream>>>(xb, w1t, biasp, W2, b2, out);
}